// Round 4
// baseline (163.481 us; speedup 1.0000x reference)
//
#include <hip/hip_runtime.h>
#include <hip/hip_bf16.h>

#define NROWS 2048
#define HST 68   // LDS row stride in floats: 272 B, 16B-aligned

typedef __attribute__((ext_vector_type(8))) short bf16x8;
typedef __attribute__((ext_vector_type(4))) float f32x4;

union Frag { bf16x8 v; unsigned u[4]; };

// pack two fp32 -> packed bf16 (RNE). gfx950 has v_cvt_pk_bf16_f32.
#if defined(__has_builtin) && __has_builtin(__builtin_amdgcn_cvt_pk_bf16_f32)
typedef __bf16 bfv2 __attribute__((ext_vector_type(2)));
static __device__ __forceinline__ unsigned cvt2(float a, float b) {
    union { bfv2 v; unsigned u; } c;
    c.v = __builtin_amdgcn_cvt_pk_bf16_f32(a, b);
    return c.u;
}
#else
static __device__ __forceinline__ unsigned short f2bf_(float f) {
    union { float f; unsigned u; } v; v.f = f;
    return (unsigned short)((v.u + 0x7fffu + ((v.u >> 16) & 1u)) >> 16);
}
static __device__ __forceinline__ unsigned cvt2(float a, float b) {
    return (unsigned)f2bf_(a) | ((unsigned)f2bf_(b) << 16);
}
#endif

// Workspace layout (floats):
//   hi_ws : [0, 2048*64)
//   hj_ws : [2048*64, 2*2048*64)
//   TI    : 42 rows x 64  (i-side tables: subj 0-15, rel 16-24, obj 25-40, const 41)
//   TJ    : 42 rows x 64  (j-side)
#define TI_OFF (2 * NROWS * 64)
#define TJ_OFF (TI_OFF + 42 * 64)

// ---------------- Kernel A1: build linear tables ----------------
// e = es[s] + er[r] + eo[o] + proj_b  (blockwise-linear projection), so
// hi[n] = Hs_i[s] + Hr_i[r] + Ho_i[o] + c_i  with 41-row tables + const row.
// Each of 8 blocks redundantly computes etab (tiny), then 1/8 of stage 2.
__global__ __launch_bounds__(256) void table_kernel(
    const float* __restrict__ subj_table, const float* __restrict__ rel_table,
    const float* __restrict__ obj_table,
    const float* __restrict__ proj_w, const float* __restrict__ proj_b,
    const float* __restrict__ w1, const float* __restrict__ b1,
    float* __restrict__ ws)
{
    __shared__ float etab[42 * 64];
    const int t = threadIdx.x;

    // stage 1: e-tables (42x64); row 41 = proj_b itself
    for (int e = t; e < 42 * 64; e += 256) {
        const int r = e >> 6, d = e & 63;
        float acc;
        if (r == 41) {
            acc = proj_b[d];
        } else {
            const float* src;
            int off;
            if (r < 16)      { src = subj_table + r * 64;        off = 0;   }
            else if (r < 25) { src = rel_table + (r - 16) * 64;  off = 64;  }
            else             { src = obj_table + (r - 25) * 64;  off = 128; }
            const float* wrow = proj_w + d * 192 + off;
            acc = 0.f;
            #pragma unroll 8
            for (int k = 0; k < 64; ++k) acc = fmaf(src[k], wrow[k], acc);
        }
        etab[e] = acc;
    }
    __syncthreads();

    // stage 2: H tables, 42x64x2 = 5376 outputs split across 8 blocks
    float* TI = ws + TI_OFF;
    float* TJ = ws + TJ_OFF;
    const int g0 = blockIdx.x * 672;
    for (int e = t; e < 672; e += 256) {
        const int g = g0 + e;
        const int side = g >= 42 * 64;            // 0 = i-side, 1 = j-side
        const int e2 = g - side * 42 * 64;
        const int r = e2 >> 6, d = e2 & 63;
        float acc = (!side && r == 41) ? b1[d] : 0.f;
        const float* wrow = w1 + d * 128 + side * 64;
        const float* er = etab + r * 64;
        #pragma unroll 8
        for (int k = 0; k < 64; ++k) acc = fmaf(er[k], wrow[k], acc);
        (side ? TJ : TI)[e2] = acc;
    }
}

// ---------------- Kernel A2: gather-add hi/hj ----------------
__global__ __launch_bounds__(256) void gather_kernel(
    const int* __restrict__ subj_idx, const int* __restrict__ rel_idx,
    const int* __restrict__ obj_idx, float* __restrict__ ws)
{
    const float* TI = ws + TI_OFF;
    const float* TJ = ws + TJ_OFF;
    float* hi_ws = ws;
    float* hj_ws = ws + NROWS * 64;

    const int t = threadIdx.x;
    const int n = blockIdx.x * 32 + (t >> 3);
    const int c = (t & 7) * 8;

    const int s = subj_idx[n];
    const int r = 16 + rel_idx[n];
    const int o = 25 + obj_idx[n];

    #pragma unroll
    for (int h = 0; h < 2; ++h) {
        const int cc = c + h * 4;
        const float4 a = *(const float4*)(TI + s * 64 + cc);
        const float4 b = *(const float4*)(TI + r * 64 + cc);
        const float4 d4 = *(const float4*)(TI + o * 64 + cc);
        const float4 e4 = *(const float4*)(TI + 41 * 64 + cc);
        float4 v;
        v.x = a.x + b.x + d4.x + e4.x;
        v.y = a.y + b.y + d4.y + e4.y;
        v.z = a.z + b.z + d4.z + e4.z;
        v.w = a.w + b.w + d4.w + e4.w;
        *(float4*)(hi_ws + (size_t)n * 64 + cc) = v;

        const float4 a2 = *(const float4*)(TJ + s * 64 + cc);
        const float4 b2 = *(const float4*)(TJ + r * 64 + cc);
        const float4 d2 = *(const float4*)(TJ + o * 64 + cc);
        const float4 e2 = *(const float4*)(TJ + 41 * 64 + cc);
        float4 w;
        w.x = a2.x + b2.x + d2.x + e2.x;
        w.y = a2.y + b2.y + d2.y + e2.y;
        w.z = a2.z + b2.z + d2.z + e2.z;
        w.w = a2.w + b2.w + d2.w + e2.w;
        *(float4*)(hj_ws + (size_t)n * 64 + cc) = w;
    }
}

// ---------------- Kernel B: pairwise scores via MFMA ----------------
// 32x32 pair tile / block (4 waves). Wave (wi,wj): i-half wi*16.., j-group
// wj*16+col. D = w2_tile(A, m=channel) x h(B, n=pair): channel dim lands in
// registers -> w3-dot is 8 in-register fma + 2 cross-lane shuffles.
__global__ __launch_bounds__(256, 4) void pair_kernel(
    const float* __restrict__ hi_ws, const float* __restrict__ hj_ws,
    const float* __restrict__ w2, const float* __restrict__ b2,
    const float* __restrict__ w3, const float* __restrict__ b3,
    float* __restrict__ out)
{
    const int bx = blockIdx.x, by = blockIdx.y;
    const int i0 = by * 32, j0 = bx * 32;
    const int tid = threadIdx.x;

    if (bx < by) {   // entire tile strictly below diagonal -> zeros
        const float4 z = {0.f, 0.f, 0.f, 0.f};
        ((float4*)(out + (size_t)(i0 + (tid >> 3)) * NROWS + j0))[tid & 7] = z;
        return;
    }

    __shared__ float hiL[32 * HST];

    const int lane = tid & 63;
    const int wid  = tid >> 6;
    const int col  = lane & 15;
    const int quad = lane >> 4;
    const int wj   = wid & 1;
    const int wi   = wid >> 1;

    // w2 A-frags (block-invariant): lane = channel ch_half*16+col, k = ks*32+quad*8+j
    Frag wf[2][2];
    #pragma unroll
    for (int ch = 0; ch < 2; ++ch)
        #pragma unroll
        for (int ks = 0; ks < 2; ++ks) {
            const float4* wr = (const float4*)(w2 + (ch * 16 + col) * 64 + ks * 32 + quad * 8);
            const float4 w0 = wr[0], w1v = wr[1];
            wf[ch][ks].u[0] = cvt2(w0.x, w0.y);
            wf[ch][ks].u[1] = cvt2(w0.z, w0.w);
            wf[ch][ks].u[2] = cvt2(w1v.x, w1v.y);
            wf[ch][ks].u[3] = cvt2(w1v.z, w1v.w);
        }
    // epilogue coefficients: lane's channels are quad*4+r (accA) / 16+quad*4+r (accB)
    const float4 b2A = *(const float4*)(b2 + quad * 4);
    const float4 b2B = *(const float4*)(b2 + 16 + quad * 4);
    const float4 w3A = *(const float4*)(w3 + quad * 4);
    const float4 w3B = *(const float4*)(w3 + 16 + quad * 4);
    const float b3v = b3[0];

    // stage hi rows into LDS (broadcast-read in the loop)
    {
        const int r = tid >> 3;
        const int c = (tid & 7) * 8;
        const float4* si = (const float4*)(hi_ws + (size_t)(i0 + r) * 64 + c);
        const float4 a0 = si[0], a1 = si[1];
        *(float4*)&hiL[r * HST + c] = a0;
        *(float4*)&hiL[r * HST + c + 4] = a1;
    }

    // loop-invariant hj fragment straight from global (L2-hot, once per block)
    const float* hjr = hj_ws + (size_t)(j0 + wj * 16 + col) * 64 + quad * 8;
    const float4 hj0 = *(const float4*)(hjr);
    const float4 hj1 = *(const float4*)(hjr + 4);
    const float4 hj2 = *(const float4*)(hjr + 32);
    const float4 hj3 = *(const float4*)(hjr + 36);

    __syncthreads();

    const int jg = j0 + wj * 16 + col;

    #pragma unroll 4
    for (int it = 0; it < 16; ++it) {
        const int il = wi * 16 + it;
        const int base = il * HST + quad * 8;
        // hi broadcast reads (same addr across the 16 lanes of a quad)
        const float4 x0 = *(const float4*)&hiL[base];
        const float4 x1 = *(const float4*)&hiL[base + 4];
        const float4 x2 = *(const float4*)&hiL[base + 32];
        const float4 x3 = *(const float4*)&hiL[base + 36];

        // h = relu(hi + hj) -> bf16 B-frags (lane: pair n=col, k=ks*32+quad*8+j)
        Frag f0, f1;
        f0.u[0] = cvt2(fmaxf(x0.x + hj0.x, 0.f), fmaxf(x0.y + hj0.y, 0.f));
        f0.u[1] = cvt2(fmaxf(x0.z + hj0.z, 0.f), fmaxf(x0.w + hj0.w, 0.f));
        f0.u[2] = cvt2(fmaxf(x1.x + hj1.x, 0.f), fmaxf(x1.y + hj1.y, 0.f));
        f0.u[3] = cvt2(fmaxf(x1.z + hj1.z, 0.f), fmaxf(x1.w + hj1.w, 0.f));
        f1.u[0] = cvt2(fmaxf(x2.x + hj2.x, 0.f), fmaxf(x2.y + hj2.y, 0.f));
        f1.u[1] = cvt2(fmaxf(x2.z + hj2.z, 0.f), fmaxf(x2.w + hj2.w, 0.f));
        f1.u[2] = cvt2(fmaxf(x3.x + hj3.x, 0.f), fmaxf(x3.y + hj3.y, 0.f));
        f1.u[3] = cvt2(fmaxf(x3.z + hj3.z, 0.f), fmaxf(x3.w + hj3.w, 0.f));

        f32x4 accA = {0.f, 0.f, 0.f, 0.f};
        f32x4 accB = {0.f, 0.f, 0.f, 0.f};
        accA = __builtin_amdgcn_mfma_f32_16x16x32_bf16(wf[0][0].v, f0.v, accA, 0, 0, 0);
        accA = __builtin_amdgcn_mfma_f32_16x16x32_bf16(wf[0][1].v, f1.v, accA, 0, 0, 0);
        accB = __builtin_amdgcn_mfma_f32_16x16x32_bf16(wf[1][0].v, f0.v, accB, 0, 0, 0);
        accB = __builtin_amdgcn_mfma_f32_16x16x32_bf16(wf[1][1].v, f1.v, accB, 0, 0, 0);

        // w3-dot over this lane's 8 channels (in-register)
        float p = w3A.x * fmaxf(accA[0] + b2A.x, 0.f)
                + w3A.y * fmaxf(accA[1] + b2A.y, 0.f)
                + w3A.z * fmaxf(accA[2] + b2A.z, 0.f)
                + w3A.w * fmaxf(accA[3] + b2A.w, 0.f)
                + w3B.x * fmaxf(accB[0] + b2B.x, 0.f)
                + w3B.y * fmaxf(accB[1] + b2B.y, 0.f)
                + w3B.z * fmaxf(accB[2] + b2B.z, 0.f)
                + w3B.w * fmaxf(accB[3] + b2B.w, 0.f);
        // reduce across the 4 quads (lanes xor 16, xor 32)
        p += __shfl_xor(p, 16, 64);
        p += __shfl_xor(p, 32, 64);

        if (quad == 0) {
            const int i = i0 + il;
            const float score = 1.f / (1.f + __expf(-(p + b3v)));
            out[(size_t)i * NROWS + jg] = (jg > i) ? score : 0.f;
        }
    }
}

extern "C" void kernel_launch(void* const* d_in, const int* in_sizes, int n_in,
                              void* d_out, int out_size, void* d_ws, size_t ws_size,
                              hipStream_t stream) {
    const int*   subj_idx   = (const int*)d_in[0];
    const int*   rel_idx    = (const int*)d_in[1];
    const int*   obj_idx    = (const int*)d_in[2];
    const float* subj_table = (const float*)d_in[3];
    const float* rel_table  = (const float*)d_in[4];
    const float* obj_table  = (const float*)d_in[5];
    const float* proj_w     = (const float*)d_in[6];
    const float* proj_b     = (const float*)d_in[7];
    const float* w1         = (const float*)d_in[8];
    const float* b1         = (const float*)d_in[9];
    const float* w2         = (const float*)d_in[10];
    const float* b2         = (const float*)d_in[11];
    const float* w3         = (const float*)d_in[12];
    const float* b3         = (const float*)d_in[13];
    float* out = (float*)d_out;
    float* ws  = (float*)d_ws;

    table_kernel<<<dim3(8), dim3(256), 0, stream>>>(
        subj_table, rel_table, obj_table, proj_w, proj_b, w1, b1, ws);

    gather_kernel<<<dim3(NROWS / 32), dim3(256), 0, stream>>>(
        subj_idx, rel_idx, obj_idx, ws);

    pair_kernel<<<dim3(NROWS / 32, NROWS / 32), dim3(256), 0, stream>>>(
        ws, ws + NROWS * 64, w2, b2, w3, b3, out);
}

// Round 5
// 140.438 us; speedup vs baseline: 1.1641x; 1.1641x over previous
//
#include <hip/hip_runtime.h>
#include <hip/hip_bf16.h>

#define NROWS 2048
#define HST 68   // LDS row stride in floats: 272 B, 16B-aligned, conflict-free broadcast reads

typedef __attribute__((ext_vector_type(8))) short bf16x8;
typedef __attribute__((ext_vector_type(4))) float f32x4;

union Frag { bf16x8 v; unsigned u[4]; };

// pack two fp32 -> packed bf16 (RNE). gfx950 has v_cvt_pk_bf16_f32.
#if defined(__has_builtin) && __has_builtin(__builtin_amdgcn_cvt_pk_bf16_f32)
typedef __bf16 bfv2 __attribute__((ext_vector_type(2)));
static __device__ __forceinline__ unsigned cvt2(float a, float b) {
    union { bfv2 v; unsigned u; } c;
    c.v = __builtin_amdgcn_cvt_pk_bf16_f32(a, b);
    return c.u;
}
#else
static __device__ __forceinline__ unsigned short f2bf_(float f) {
    union { float f; unsigned u; } v; v.f = f;
    return (unsigned short)((v.u + 0x7fffu + ((v.u >> 16) & 1u)) >> 16);
}
static __device__ __forceinline__ unsigned cvt2(float a, float b) {
    return (unsigned)f2bf_(a) | ((unsigned)f2bf_(b) << 16);
}
#endif

static __device__ __forceinline__ f32x4 vmax0(f32x4 a) {
    return __builtin_elementwise_max(a, (f32x4)0.f);
}

// Workspace layout (floats):
//   TI   : ws[0      .. 2688)   42 rows x 64 (i-side: subj 0-15, rel 16-24, obj 25-40, const 41)
//   TJ   : ws[2688   .. 5376)   42 rows x 64 (j-side)
//   ETAB : ws[5376   .. 8064)   42 rows x 64 (e-space tables)
#define TJ_OFF  2688
#define ET_OFF  5376

// ---------------- Kernel T1: e-tables ----------------
// etab[r] = emb_row(r) @ proj_w_seg.T  (row 41 = proj_b). Lane = k (summed dim)
// -> all proj_w loads coalesced; 64->1 butterfly reduce, 4 chains for latency.
__global__ __launch_bounds__(256) void etab_kernel(
    const float* __restrict__ subj_table, const float* __restrict__ rel_table,
    const float* __restrict__ obj_table,
    const float* __restrict__ proj_w, const float* __restrict__ proj_b,
    float* __restrict__ ws)
{
    float* ET = ws + ET_OFF;
    const int r = blockIdx.x;            // 0..41
    const int lane = threadIdx.x & 63;
    const int w = threadIdx.x >> 6;

    if (r == 41) {
        if (threadIdx.x < 64) ET[41 * 64 + threadIdx.x] = proj_b[threadIdx.x];
        return;
    }
    const float* src; int off;
    if (r < 16)      { src = subj_table + r * 64;        off = 0;   }
    else if (r < 25) { src = rel_table + (r - 16) * 64;  off = 64;  }
    else             { src = obj_table + (r - 25) * 64;  off = 128; }
    const float sv = src[lane];

    #pragma unroll
    for (int t = 0; t < 4; ++t) {
        const int d0 = w * 16 + t * 4;
        float p0 = sv * proj_w[(d0 + 0) * 192 + off + lane];
        float p1 = sv * proj_w[(d0 + 1) * 192 + off + lane];
        float p2 = sv * proj_w[(d0 + 2) * 192 + off + lane];
        float p3 = sv * proj_w[(d0 + 3) * 192 + off + lane];
        #pragma unroll
        for (int m = 1; m < 64; m <<= 1) {
            p0 += __shfl_xor(p0, m, 64);
            p1 += __shfl_xor(p1, m, 64);
            p2 += __shfl_xor(p2, m, 64);
            p3 += __shfl_xor(p3, m, 64);
        }
        if (lane == 0) {
            ET[r * 64 + d0 + 0] = p0;
            ET[r * 64 + d0 + 1] = p1;
            ET[r * 64 + d0 + 2] = p2;
            ET[r * 64 + d0 + 3] = p3;
        }
    }
}

// ---------------- Kernel T2: H-tables ----------------
// TI[r] = etab[r] @ w1[:, :64].T (+b1 on const row); TJ[r] = etab[r] @ w1[:, 64:].T
__global__ __launch_bounds__(256) void htab_kernel(
    const float* __restrict__ w1, const float* __restrict__ b1,
    float* __restrict__ ws)
{
    const float* ET = ws + ET_OFF;
    const int b = blockIdx.x;            // 0..83
    const int side = b & 1;
    const int r = b >> 1;
    const int lane = threadIdx.x & 63;
    const int w = threadIdx.x >> 6;

    float* dst = ws + (side ? TJ_OFF : 0);
    const float sv = ET[r * 64 + lane];
    const int woff = side * 64;

    #pragma unroll
    for (int t = 0; t < 4; ++t) {
        const int d0 = w * 16 + t * 4;
        float p0 = sv * w1[(d0 + 0) * 128 + woff + lane];
        float p1 = sv * w1[(d0 + 1) * 128 + woff + lane];
        float p2 = sv * w1[(d0 + 2) * 128 + woff + lane];
        float p3 = sv * w1[(d0 + 3) * 128 + woff + lane];
        #pragma unroll
        for (int m = 1; m < 64; m <<= 1) {
            p0 += __shfl_xor(p0, m, 64);
            p1 += __shfl_xor(p1, m, 64);
            p2 += __shfl_xor(p2, m, 64);
            p3 += __shfl_xor(p3, m, 64);
        }
        if (lane == 0) {
            const bool cst = (side == 0) && (r == 41);
            dst[r * 64 + d0 + 0] = p0 + (cst ? b1[d0 + 0] : 0.f);
            dst[r * 64 + d0 + 1] = p1 + (cst ? b1[d0 + 1] : 0.f);
            dst[r * 64 + d0 + 2] = p2 + (cst ? b1[d0 + 2] : 0.f);
            dst[r * 64 + d0 + 3] = p3 + (cst ? b1[d0 + 3] : 0.f);
        }
    }
}

// ---------------- Kernel B: pairwise scores via MFMA ----------------
// 32x32 pair tile / block (4 waves). Prologue gathers hi/hj rows from the
// 21 KB TI/TJ tables (L1/L2-hot) straight into LDS. Wave (wi,wj): i-half
// wi*16.., j-group wj*16+col. D = w2(A, m=channel) x h(B, n=pair).
__global__ __launch_bounds__(256, 4) void pair_kernel(
    const int* __restrict__ subj_idx, const int* __restrict__ rel_idx,
    const int* __restrict__ obj_idx,
    const float* __restrict__ tab,
    const float* __restrict__ w2, const float* __restrict__ b2,
    const float* __restrict__ w3, const float* __restrict__ b3,
    float* __restrict__ out)
{
    const int bx = blockIdx.x, by = blockIdx.y;
    const int i0 = by * 32, j0 = bx * 32;
    const int tid = threadIdx.x;

    if (bx < by) {   // entire tile strictly below diagonal -> zeros
        const float4 z = {0.f, 0.f, 0.f, 0.f};
        ((float4*)(out + (size_t)(i0 + (tid >> 3)) * NROWS + j0))[tid & 7] = z;
        return;
    }

    __shared__ float hiL[32 * HST];
    __shared__ float hjL[32 * HST];

    const int lane = tid & 63;
    const int wid  = tid >> 6;
    const int col  = lane & 15;
    const int quad = lane >> 4;
    const int wj   = wid & 1;
    const int wi   = wid >> 1;

    // ---- fused gather: hi/hj rows = TI/TJ[s] + [16+r] + [25+o] + [41] ----
    {
        const int rr = tid >> 3;             // 0..31
        const int cc = (tid & 7) * 8;
        const int iR = i0 + rr, jR = j0 + rr;
        const int si = subj_idx[iR], ri = 16 + rel_idx[iR], oi = 25 + obj_idx[iR];
        const int sj = subj_idx[jR], rj = 16 + rel_idx[jR], oj = 25 + obj_idx[jR];
        const float* TI = tab;
        const float* TJ = tab + TJ_OFF;
        #pragma unroll
        for (int h = 0; h < 2; ++h) {
            const int c = cc + h * 4;
            const f32x4 v = *(const f32x4*)(TI + si * 64 + c)
                          + *(const f32x4*)(TI + ri * 64 + c)
                          + *(const f32x4*)(TI + oi * 64 + c)
                          + *(const f32x4*)(TI + 41 * 64 + c);
            *(f32x4*)&hiL[rr * HST + c] = v;
            const f32x4 u = *(const f32x4*)(TJ + sj * 64 + c)
                          + *(const f32x4*)(TJ + rj * 64 + c)
                          + *(const f32x4*)(TJ + oj * 64 + c)
                          + *(const f32x4*)(TJ + 41 * 64 + c);
            *(f32x4*)&hjL[rr * HST + c] = u;
        }
    }

    // w2 A-frags (block-invariant): lane = channel ch*16+col, k = ks*32+quad*8+j
    Frag wf[2][2];
    #pragma unroll
    for (int ch = 0; ch < 2; ++ch)
        #pragma unroll
        for (int ks = 0; ks < 2; ++ks) {
            const f32x4* wr = (const f32x4*)(w2 + (ch * 16 + col) * 64 + ks * 32 + quad * 8);
            const f32x4 w0 = wr[0], w1v = wr[1];
            wf[ch][ks].u[0] = cvt2(w0[0], w0[1]);
            wf[ch][ks].u[1] = cvt2(w0[2], w0[3]);
            wf[ch][ks].u[2] = cvt2(w1v[0], w1v[1]);
            wf[ch][ks].u[3] = cvt2(w1v[2], w1v[3]);
        }
    // epilogue coefficients: lane's channels are quad*4+r (accA) / 16+quad*4+r (accB)
    const f32x4 b2A = *(const f32x4*)(b2 + quad * 4);
    const f32x4 b2B = *(const f32x4*)(b2 + 16 + quad * 4);
    const f32x4 w3A = *(const f32x4*)(w3 + quad * 4);
    const f32x4 w3B = *(const f32x4*)(w3 + 16 + quad * 4);
    const float b3v = b3[0];

    __syncthreads();

    // loop-invariant hj fragment from LDS (cheap to re-read if regalloc sinks it)
    const int hjb = (wj * 16 + col) * HST + quad * 8;
    const f32x4 hj0 = *(const f32x4*)&hjL[hjb];
    const f32x4 hj1 = *(const f32x4*)&hjL[hjb + 4];
    const f32x4 hj2 = *(const f32x4*)&hjL[hjb + 32];
    const f32x4 hj3 = *(const f32x4*)&hjL[hjb + 36];

    const int jg = j0 + wj * 16 + col;

    #pragma unroll 2
    for (int it = 0; it < 16; ++it) {
        const int il = wi * 16 + it;
        const int base = il * HST + quad * 8;
        // hi broadcast reads (same addr across the 16 lanes of a quad)
        const f32x4 x0 = *(const f32x4*)&hiL[base];
        const f32x4 x1 = *(const f32x4*)&hiL[base + 4];
        const f32x4 x2 = *(const f32x4*)&hiL[base + 32];
        const f32x4 x3 = *(const f32x4*)&hiL[base + 36];

        // h = relu(hi + hj) via packed f32 ops -> bf16 B-frags
        const f32x4 s0 = vmax0(x0 + hj0);
        const f32x4 s1 = vmax0(x1 + hj1);
        const f32x4 s2 = vmax0(x2 + hj2);
        const f32x4 s3 = vmax0(x3 + hj3);

        Frag f0, f1;
        f0.u[0] = cvt2(s0[0], s0[1]); f0.u[1] = cvt2(s0[2], s0[3]);
        f0.u[2] = cvt2(s1[0], s1[1]); f0.u[3] = cvt2(s1[2], s1[3]);
        f1.u[0] = cvt2(s2[0], s2[1]); f1.u[1] = cvt2(s2[2], s2[3]);
        f1.u[2] = cvt2(s3[0], s3[1]); f1.u[3] = cvt2(s3[2], s3[3]);

        f32x4 accA = {0.f, 0.f, 0.f, 0.f};
        f32x4 accB = {0.f, 0.f, 0.f, 0.f};
        accA = __builtin_amdgcn_mfma_f32_16x16x32_bf16(wf[0][0].v, f0.v, accA, 0, 0, 0);
        accA = __builtin_amdgcn_mfma_f32_16x16x32_bf16(wf[0][1].v, f1.v, accA, 0, 0, 0);
        accB = __builtin_amdgcn_mfma_f32_16x16x32_bf16(wf[1][0].v, f0.v, accB, 0, 0, 0);
        accB = __builtin_amdgcn_mfma_f32_16x16x32_bf16(wf[1][1].v, f1.v, accB, 0, 0, 0);

        // epilogue: relu(+b2) then w3-dot, packed
        const f32x4 ra = vmax0(accA + b2A);
        const f32x4 rb = vmax0(accB + b2B);
        const f32x4 t4 = ra * w3A + rb * w3B;
        float p = (t4[0] + t4[1]) + (t4[2] + t4[3]);
        p += __shfl_xor(p, 16, 64);
        p += __shfl_xor(p, 32, 64);

        if (quad == 0) {
            const int i = i0 + il;
            const float score = 1.f / (1.f + __expf(-(p + b3v)));
            out[(size_t)i * NROWS + jg] = (jg > i) ? score : 0.f;
        }
    }
}

extern "C" void kernel_launch(void* const* d_in, const int* in_sizes, int n_in,
                              void* d_out, int out_size, void* d_ws, size_t ws_size,
                              hipStream_t stream) {
    const int*   subj_idx   = (const int*)d_in[0];
    const int*   rel_idx    = (const int*)d_in[1];
    const int*   obj_idx    = (const int*)d_in[2];
    const float* subj_table = (const float*)d_in[3];
    const float* rel_table  = (const float*)d_in[4];
    const float* obj_table  = (const float*)d_in[5];
    const float* proj_w     = (const float*)d_in[6];
    const float* proj_b     = (const float*)d_in[7];
    const float* w1         = (const float*)d_in[8];
    const float* b1         = (const float*)d_in[9];
    const float* w2         = (const float*)d_in[10];
    const float* b2         = (const float*)d_in[11];
    const float* w3         = (const float*)d_in[12];
    const float* b3         = (const float*)d_in[13];
    float* out = (float*)d_out;
    float* ws  = (float*)d_ws;

    etab_kernel<<<dim3(42), dim3(256), 0, stream>>>(
        subj_table, rel_table, obj_table, proj_w, proj_b, ws);

    htab_kernel<<<dim3(84), dim3(256), 0, stream>>>(w1, b1, ws);

    pair_kernel<<<dim3(NROWS / 32, NROWS / 32), dim3(256), 0, stream>>>(
        subj_idx, rel_idx, obj_idx, ws, w2, b2, w3, b3, out);
}

// Round 7
// 120.084 us; speedup vs baseline: 1.3614x; 1.1695x over previous
//
#include <hip/hip_runtime.h>
#include <hip/hip_bf16.h>

#define NROWS 2048
#define HH 72    // LDS row stride in halves: 144 B, 16B-aligned, rotates banks by 4/row

typedef __attribute__((ext_vector_type(4))) float f32x4;
typedef _Float16 f16x2 __attribute__((ext_vector_type(2)));
typedef _Float16 f16x8 __attribute__((ext_vector_type(8)));
typedef __fp16 fp16x2_raw __attribute__((ext_vector_type(2)));

union H8 { f16x8 v; f16x2 h2[4]; };

static __device__ __forceinline__ f32x4 vmax0(f32x4 a) {
    return __builtin_elementwise_max(a, (f32x4)0.f);
}
static __device__ __forceinline__ f16x8 hmax0(f16x8 a) {
    return __builtin_elementwise_max(a, (f16x8)(_Float16)0.f);
}
// v_cvt_pkrtz_f16_f32: returns __fp16x2; bit-cast to our _Float16x2
static __device__ __forceinline__ f16x2 pkrtz(float a, float b) {
    union { fp16x2_raw r; f16x2 f; } c;
    c.r = __builtin_amdgcn_cvt_pkrtz(a, b);
    return c.f;
}

// Workspace layout (floats):
//   TI   : ws[0    .. 2688)   42 rows x 64 (i-side: subj 0-15, rel 16-24, obj 25-40, const 41)
//   TJ   : ws[2688 .. 5376)   42 rows x 64 (j-side)
//   ETAB : ws[5376 .. 8064)   42 rows x 64 (e-space tables)
#define TJ_OFF  2688
#define ET_OFF  5376

// ---------------- Kernel T1: e-tables ----------------
__global__ __launch_bounds__(256) void etab_kernel(
    const float* __restrict__ subj_table, const float* __restrict__ rel_table,
    const float* __restrict__ obj_table,
    const float* __restrict__ proj_w, const float* __restrict__ proj_b,
    float* __restrict__ ws)
{
    float* ET = ws + ET_OFF;
    const int r = blockIdx.x;            // 0..41
    const int lane = threadIdx.x & 63;
    const int w = threadIdx.x >> 6;

    if (r == 41) {
        if (threadIdx.x < 64) ET[41 * 64 + threadIdx.x] = proj_b[threadIdx.x];
        return;
    }
    const float* src; int off;
    if (r < 16)      { src = subj_table + r * 64;        off = 0;   }
    else if (r < 25) { src = rel_table + (r - 16) * 64;  off = 64;  }
    else             { src = obj_table + (r - 25) * 64;  off = 128; }
    const float sv = src[lane];

    #pragma unroll
    for (int t = 0; t < 4; ++t) {
        const int d0 = w * 16 + t * 4;
        float p0 = sv * proj_w[(d0 + 0) * 192 + off + lane];
        float p1 = sv * proj_w[(d0 + 1) * 192 + off + lane];
        float p2 = sv * proj_w[(d0 + 2) * 192 + off + lane];
        float p3 = sv * proj_w[(d0 + 3) * 192 + off + lane];
        #pragma unroll
        for (int m = 1; m < 64; m <<= 1) {
            p0 += __shfl_xor(p0, m, 64);
            p1 += __shfl_xor(p1, m, 64);
            p2 += __shfl_xor(p2, m, 64);
            p3 += __shfl_xor(p3, m, 64);
        }
        if (lane == 0) {
            ET[r * 64 + d0 + 0] = p0;
            ET[r * 64 + d0 + 1] = p1;
            ET[r * 64 + d0 + 2] = p2;
            ET[r * 64 + d0 + 3] = p3;
        }
    }
}

// ---------------- Kernel T2: H-tables ----------------
__global__ __launch_bounds__(256) void htab_kernel(
    const float* __restrict__ w1, const float* __restrict__ b1,
    float* __restrict__ ws)
{
    const float* ET = ws + ET_OFF;
    const int b = blockIdx.x;            // 0..83
    const int side = b & 1;
    const int r = b >> 1;
    const int lane = threadIdx.x & 63;
    const int w = threadIdx.x >> 6;

    float* dst = ws + (side ? TJ_OFF : 0);
    const float sv = ET[r * 64 + lane];
    const int woff = side * 64;

    #pragma unroll
    for (int t = 0; t < 4; ++t) {
        const int d0 = w * 16 + t * 4;
        float p0 = sv * w1[(d0 + 0) * 128 + woff + lane];
        float p1 = sv * w1[(d0 + 1) * 128 + woff + lane];
        float p2 = sv * w1[(d0 + 2) * 128 + woff + lane];
        float p3 = sv * w1[(d0 + 3) * 128 + woff + lane];
        #pragma unroll
        for (int m = 1; m < 64; m <<= 1) {
            p0 += __shfl_xor(p0, m, 64);
            p1 += __shfl_xor(p1, m, 64);
            p2 += __shfl_xor(p2, m, 64);
            p3 += __shfl_xor(p3, m, 64);
        }
        if (lane == 0) {
            const bool cst = (side == 0) && (r == 41);
            dst[r * 64 + d0 + 0] = p0 + (cst ? b1[d0 + 0] : 0.f);
            dst[r * 64 + d0 + 1] = p1 + (cst ? b1[d0 + 1] : 0.f);
            dst[r * 64 + d0 + 2] = p2 + (cst ? b1[d0 + 2] : 0.f);
            dst[r * 64 + d0 + 3] = p3 + (cst ? b1[d0 + 3] : 0.f);
        }
    }
}

// ---------------- Kernel B: pairwise scores via fp16 MFMA ----------------
// 32x32 pair tile / block (4 waves). Prologue: gather hi/hj rows from TI/TJ
// (fp32 sums) -> fp16 LDS. Inner loop: v_pk_add_f16 + v_pk_max_f16 build the
// MFMA A-operand directly (no per-iter cvt). acc initialized with b2.
__global__ __launch_bounds__(256, 4) void pair_kernel(
    const int* __restrict__ subj_idx, const int* __restrict__ rel_idx,
    const int* __restrict__ obj_idx,
    const float* __restrict__ tab,
    const float* __restrict__ w2, const float* __restrict__ b2,
    const float* __restrict__ w3, const float* __restrict__ b3,
    float* __restrict__ out)
{
    const int bx = blockIdx.x, by = blockIdx.y;
    const int i0 = by * 32, j0 = bx * 32;
    const int tid = threadIdx.x;

    if (bx < by) {   // entire tile strictly below diagonal -> zeros
        const float4 z = {0.f, 0.f, 0.f, 0.f};
        ((float4*)(out + (size_t)(i0 + (tid >> 3)) * NROWS + j0))[tid & 7] = z;
        return;
    }

    __shared__ _Float16 hiL[32 * HH];   // 4608 B
    __shared__ _Float16 hjL[32 * HH];   // 4608 B

    const int lane = tid & 63;
    const int wid  = tid >> 6;
    const int col  = lane & 15;
    const int quad = lane >> 4;
    const int wj   = wid & 1;
    const int wi   = wid >> 1;

    // ---- fused gather: row = T[s] + T[16+r] + T[25+o] + T[41], fp32 -> fp16 LDS ----
    {
        const int rr = tid >> 3;             // 0..31
        const int cc = (tid & 7) * 8;        // halves / floats
        const int iR = i0 + rr, jR = j0 + rr;
        const int si = subj_idx[iR], ri = 16 + rel_idx[iR], oi = 25 + obj_idx[iR];
        const int sj = subj_idx[jR], rj = 16 + rel_idx[jR], oj = 25 + obj_idx[jR];
        const float* TI = tab;
        const float* TJ = tab + TJ_OFF;
        const f32x4 v0 = *(const f32x4*)(TI + si * 64 + cc)
                       + *(const f32x4*)(TI + ri * 64 + cc)
                       + *(const f32x4*)(TI + oi * 64 + cc)
                       + *(const f32x4*)(TI + 41 * 64 + cc);
        const f32x4 v1 = *(const f32x4*)(TI + si * 64 + cc + 4)
                       + *(const f32x4*)(TI + ri * 64 + cc + 4)
                       + *(const f32x4*)(TI + oi * 64 + cc + 4)
                       + *(const f32x4*)(TI + 41 * 64 + cc + 4);
        H8 hp;
        hp.h2[0] = pkrtz(v0[0], v0[1]); hp.h2[1] = pkrtz(v0[2], v0[3]);
        hp.h2[2] = pkrtz(v1[0], v1[1]); hp.h2[3] = pkrtz(v1[2], v1[3]);
        *(f16x8*)&hiL[rr * HH + cc] = hp.v;

        const f32x4 u0 = *(const f32x4*)(TJ + sj * 64 + cc)
                       + *(const f32x4*)(TJ + rj * 64 + cc)
                       + *(const f32x4*)(TJ + oj * 64 + cc)
                       + *(const f32x4*)(TJ + 41 * 64 + cc);
        const f32x4 u1 = *(const f32x4*)(TJ + sj * 64 + cc + 4)
                       + *(const f32x4*)(TJ + rj * 64 + cc + 4)
                       + *(const f32x4*)(TJ + oj * 64 + cc + 4)
                       + *(const f32x4*)(TJ + 41 * 64 + cc + 4);
        H8 hq;
        hq.h2[0] = pkrtz(u0[0], u0[1]); hq.h2[1] = pkrtz(u0[2], u0[3]);
        hq.h2[2] = pkrtz(u1[0], u1[1]); hq.h2[3] = pkrtz(u1[2], u1[3]);
        *(f16x8*)&hjL[rr * HH + cc] = hq.v;
    }

    // w2 A-frags (block-invariant): lane = channel ch*16+col, k = ks*32+quad*8+j
    H8 wf[2][2];
    #pragma unroll
    for (int ch = 0; ch < 2; ++ch)
        #pragma unroll
        for (int ks = 0; ks < 2; ++ks) {
            const f32x4* wr = (const f32x4*)(w2 + (ch * 16 + col) * 64 + ks * 32 + quad * 8);
            const f32x4 w0 = wr[0], w1v = wr[1];
            wf[ch][ks].h2[0] = pkrtz(w0[0], w0[1]);
            wf[ch][ks].h2[1] = pkrtz(w0[2], w0[3]);
            wf[ch][ks].h2[2] = pkrtz(w1v[0], w1v[1]);
            wf[ch][ks].h2[3] = pkrtz(w1v[2], w1v[3]);
        }
    // epilogue coefficients: lane's channels are quad*4+r (accA) / 16+quad*4+r (accB)
    const f32x4 b2A = *(const f32x4*)(b2 + quad * 4);
    const f32x4 b2B = *(const f32x4*)(b2 + 16 + quad * 4);
    const f32x4 w3A = *(const f32x4*)(w3 + quad * 4);
    const f32x4 w3B = *(const f32x4*)(w3 + 16 + quad * 4);
    const float b3v = b3[0];

    __syncthreads();

    // loop-invariant hj fragments (this wave's 16 j's; lane's j = wj*16+col)
    const int hjb = (wj * 16 + col) * HH + quad * 8;
    const f16x8 hj0 = *(const f16x8*)&hjL[hjb];        // ks=0
    const f16x8 hj1 = *(const f16x8*)&hjL[hjb + 32];   // ks=1

    const int jg = j0 + wj * 16 + col;

    #pragma unroll 4
    for (int it = 0; it < 16; ++it) {
        const int il = wi * 16 + it;
        const int base = il * HH + quad * 8;
        // hi broadcast reads (same addr across the 16 lanes of a quad)
        const f16x8 x0 = *(const f16x8*)&hiL[base];
        const f16x8 x1 = *(const f16x8*)&hiL[base + 32];

        // h = relu(hi + hj), all fp16 packed -> MFMA operand directly
        const f16x8 f0 = hmax0(x0 + hj0);
        const f16x8 f1 = hmax0(x1 + hj1);

        f32x4 accA = b2A;   // b2 folded into accumulator init
        f32x4 accB = b2B;
        accA = __builtin_amdgcn_mfma_f32_16x16x32_f16(wf[0][0].v, f0, accA, 0, 0, 0);
        accA = __builtin_amdgcn_mfma_f32_16x16x32_f16(wf[0][1].v, f1, accA, 0, 0, 0);
        accB = __builtin_amdgcn_mfma_f32_16x16x32_f16(wf[1][0].v, f0, accB, 0, 0, 0);
        accB = __builtin_amdgcn_mfma_f32_16x16x32_f16(wf[1][1].v, f1, accB, 0, 0, 0);

        // epilogue: relu then w3-dot, packed f32
        const f32x4 ra = vmax0(accA);
        const f32x4 rb = vmax0(accB);
        const f32x4 t4 = ra * w3A + rb * w3B;
        float p = (t4[0] + t4[1]) + (t4[2] + t4[3]);
        p += __shfl_xor(p, 16, 64);
        p += __shfl_xor(p, 32, 64);

        if (quad == 0) {
            const int i = i0 + il;
            const float score = 1.f / (1.f + __expf(-(p + b3v)));
            out[(size_t)i * NROWS + jg] = (jg > i) ? score : 0.f;
        }
    }
}

extern "C" void kernel_launch(void* const* d_in, const int* in_sizes, int n_in,
                              void* d_out, int out_size, void* d_ws, size_t ws_size,
                              hipStream_t stream) {
    const int*   subj_idx   = (const int*)d_in[0];
    const int*   rel_idx    = (const int*)d_in[1];
    const int*   obj_idx    = (const int*)d_in[2];
    const float* subj_table = (const float*)d_in[3];
    const float* rel_table  = (const float*)d_in[4];
    const float* obj_table  = (const float*)d_in[5];
    const float* proj_w     = (const float*)d_in[6];
    const float* proj_b     = (const float*)d_in[7];
    const float* w1         = (const float*)d_in[8];
    const float* b1         = (const float*)d_in[9];
    const float* w2         = (const float*)d_in[10];
    const float* b2         = (const float*)d_in[11];
    const float* w3         = (const float*)d_in[12];
    const float* b3         = (const float*)d_in[13];
    float* out = (float*)d_out;
    float* ws  = (float*)d_ws;

    etab_kernel<<<dim3(42), dim3(256), 0, stream>>>(
        subj_table, rel_table, obj_table, proj_w, proj_b, ws);

    htab_kernel<<<dim3(84), dim3(256), 0, stream>>>(w1, b1, ws);

    pair_kernel<<<dim3(NROWS / 32, NROWS / 32), dim3(256), 0, stream>>>(
        subj_idx, rel_idx, obj_idx, ws, w2, b2, w3, b3, out);
}

// Round 8
// 115.907 us; speedup vs baseline: 1.4105x; 1.0360x over previous
//
#include <hip/hip_runtime.h>
#include <hip/hip_bf16.h>

#define NROWS 2048
#define HH 72    // LDS row stride in halves: 144 B, 16B-aligned

typedef __attribute__((ext_vector_type(4))) float f32x4;
typedef _Float16 f16x2 __attribute__((ext_vector_type(2)));
typedef _Float16 f16x8 __attribute__((ext_vector_type(8)));
typedef __fp16 fp16x2_raw __attribute__((ext_vector_type(2)));

union H8 { f16x8 v; f16x2 h2[4]; };

static __device__ __forceinline__ f32x4 vmax0(f32x4 a) {
    return __builtin_elementwise_max(a, (f32x4)0.f);
}
static __device__ __forceinline__ f16x8 hmax0(f16x8 a) {
    return __builtin_elementwise_max(a, (f16x8)(_Float16)0.f);
}
// v_cvt_pkrtz_f16_f32: returns __fp16x2; bit-cast to our _Float16x2
static __device__ __forceinline__ f16x2 pkrtz(float a, float b) {
    union { fp16x2_raw r; f16x2 f; } c;
    c.r = __builtin_amdgcn_cvt_pkrtz(a, b);
    return c.f;
}

// Workspace layout (floats):
//   TI : ws[0    .. 2688)  42 rows x 64 (i-side: subj 0-15, rel 16-24, obj 25-40, const 41)
//   TJ : ws[2688 .. 5376)  42 rows x 64 (j-side)
#define TJ_OFF  2688

// ---------------- Kernel T: fused e-table + H-table ----------------
// Block b (0..83): side=b&1, r=b>>1. Stage 1 computes ET row r into LDS
// (redundant per side pair, trivial); stage 2 computes H row -> TI/TJ.
__global__ __launch_bounds__(256) void tab_kernel(
    const float* __restrict__ subj_table, const float* __restrict__ rel_table,
    const float* __restrict__ obj_table,
    const float* __restrict__ proj_w, const float* __restrict__ proj_b,
    const float* __restrict__ w1, const float* __restrict__ b1,
    float* __restrict__ ws)
{
    __shared__ float et[64];
    const int b = blockIdx.x;            // 0..83
    const int side = b & 1;
    const int r = b >> 1;                // 0..41
    const int tid = threadIdx.x;
    const int lane = tid & 63;
    const int w = tid >> 6;

    // ---- stage 1: ET row r ----
    if (r == 41) {
        if (tid < 64) et[tid] = proj_b[tid];
    } else {
        const float* src; int off;
        if (r < 16)      { src = subj_table + r * 64;        off = 0;   }
        else if (r < 25) { src = rel_table + (r - 16) * 64;  off = 64;  }
        else             { src = obj_table + (r - 25) * 64;  off = 128; }
        const float sv = src[lane];
        #pragma unroll
        for (int t = 0; t < 4; ++t) {
            const int d0 = w * 16 + t * 4;
            float p0 = sv * proj_w[(d0 + 0) * 192 + off + lane];
            float p1 = sv * proj_w[(d0 + 1) * 192 + off + lane];
            float p2 = sv * proj_w[(d0 + 2) * 192 + off + lane];
            float p3 = sv * proj_w[(d0 + 3) * 192 + off + lane];
            #pragma unroll
            for (int m = 1; m < 64; m <<= 1) {
                p0 += __shfl_xor(p0, m, 64);
                p1 += __shfl_xor(p1, m, 64);
                p2 += __shfl_xor(p2, m, 64);
                p3 += __shfl_xor(p3, m, 64);
            }
            if (lane == 0) {
                et[d0 + 0] = p0; et[d0 + 1] = p1;
                et[d0 + 2] = p2; et[d0 + 3] = p3;
            }
        }
    }
    __syncthreads();

    // ---- stage 2: H row ----
    float* dst = ws + (side ? TJ_OFF : 0);
    const float sv2 = et[lane];
    const int woff = side * 64;
    #pragma unroll
    for (int t = 0; t < 4; ++t) {
        const int d0 = w * 16 + t * 4;
        float p0 = sv2 * w1[(d0 + 0) * 128 + woff + lane];
        float p1 = sv2 * w1[(d0 + 1) * 128 + woff + lane];
        float p2 = sv2 * w1[(d0 + 2) * 128 + woff + lane];
        float p3 = sv2 * w1[(d0 + 3) * 128 + woff + lane];
        #pragma unroll
        for (int m = 1; m < 64; m <<= 1) {
            p0 += __shfl_xor(p0, m, 64);
            p1 += __shfl_xor(p1, m, 64);
            p2 += __shfl_xor(p2, m, 64);
            p3 += __shfl_xor(p3, m, 64);
        }
        if (lane == 0) {
            const bool cst = (side == 0) && (r == 41);
            dst[r * 64 + d0 + 0] = p0 + (cst ? b1[d0 + 0] : 0.f);
            dst[r * 64 + d0 + 1] = p1 + (cst ? b1[d0 + 1] : 0.f);
            dst[r * 64 + d0 + 2] = p2 + (cst ? b1[d0 + 2] : 0.f);
            dst[r * 64 + d0 + 3] = p3 + (cst ? b1[d0 + 3] : 0.f);
        }
    }
}

// ---------------- Kernel B: pairwise scores via fp16 MFMA ----------------
// 32x32 pair tile / block (4 waves). Inner loop: 2 ds_read_b128 + packed fp16
// add/max -> 4 MFMA -> in-register w3 dot -> ONE fp32 LDS partial per lane.
// Deferred wave-local epilogue: reduce 4 quad partials, sigmoid, coalesced
// dwordx4 stores. No shuffles / sigmoid / scalar stores in the loop.
#define PSTR 68   // partial row stride (floats): breaks 64-stride banking in final reads

__global__ __launch_bounds__(256, 4) void pair_kernel(
    const int* __restrict__ subj_idx, const int* __restrict__ rel_idx,
    const int* __restrict__ obj_idx,
    const float* __restrict__ tab,
    const float* __restrict__ w2, const float* __restrict__ b2,
    const float* __restrict__ w3, const float* __restrict__ b3,
    float* __restrict__ out)
{
    const int bx = blockIdx.x, by = blockIdx.y;
    const int i0 = by * 32, j0 = bx * 32;
    const int tid = threadIdx.x;

    if (bx < by) {   // entire tile strictly below diagonal -> zeros
        const float4 z = {0.f, 0.f, 0.f, 0.f};
        ((float4*)(out + (size_t)(i0 + (tid >> 3)) * NROWS + j0))[tid & 7] = z;
        return;
    }

    __shared__ _Float16 hiL[32 * HH];        // 4608 B
    __shared__ _Float16 hjL[32 * HH];        // 4608 B
    __shared__ float part[4 * 16 * PSTR];    // 17408 B, per-wave slices

    const int lane = tid & 63;
    const int wid  = tid >> 6;
    const int col  = lane & 15;
    const int quad = lane >> 4;
    const int wj   = wid & 1;
    const int wi   = wid >> 1;

    // ---- fused gather: row = T[s] + T[16+r] + T[25+o] + T[41], fp32 -> fp16 LDS ----
    {
        const int rr = tid >> 3;             // 0..31
        const int cc = (tid & 7) * 8;        // halves / floats
        const int iR = i0 + rr, jR = j0 + rr;
        const int si = subj_idx[iR], ri = 16 + rel_idx[iR], oi = 25 + obj_idx[iR];
        const int sj = subj_idx[jR], rj = 16 + rel_idx[jR], oj = 25 + obj_idx[jR];
        const float* TI = tab;
        const float* TJ = tab + TJ_OFF;
        const f32x4 v0 = *(const f32x4*)(TI + si * 64 + cc)
                       + *(const f32x4*)(TI + ri * 64 + cc)
                       + *(const f32x4*)(TI + oi * 64 + cc)
                       + *(const f32x4*)(TI + 41 * 64 + cc);
        const f32x4 v1 = *(const f32x4*)(TI + si * 64 + cc + 4)
                       + *(const f32x4*)(TI + ri * 64 + cc + 4)
                       + *(const f32x4*)(TI + oi * 64 + cc + 4)
                       + *(const f32x4*)(TI + 41 * 64 + cc + 4);
        H8 hp;
        hp.h2[0] = pkrtz(v0[0], v0[1]); hp.h2[1] = pkrtz(v0[2], v0[3]);
        hp.h2[2] = pkrtz(v1[0], v1[1]); hp.h2[3] = pkrtz(v1[2], v1[3]);
        *(f16x8*)&hiL[rr * HH + cc] = hp.v;

        const f32x4 u0 = *(const f32x4*)(TJ + sj * 64 + cc)
                       + *(const f32x4*)(TJ + rj * 64 + cc)
                       + *(const f32x4*)(TJ + oj * 64 + cc)
                       + *(const f32x4*)(TJ + 41 * 64 + cc);
        const f32x4 u1 = *(const f32x4*)(TJ + sj * 64 + cc + 4)
                       + *(const f32x4*)(TJ + rj * 64 + cc + 4)
                       + *(const f32x4*)(TJ + oj * 64 + cc + 4)
                       + *(const f32x4*)(TJ + 41 * 64 + cc + 4);
        H8 hq;
        hq.h2[0] = pkrtz(u0[0], u0[1]); hq.h2[1] = pkrtz(u0[2], u0[3]);
        hq.h2[2] = pkrtz(u1[0], u1[1]); hq.h2[3] = pkrtz(u1[2], u1[3]);
        *(f16x8*)&hjL[rr * HH + cc] = hq.v;
    }

    // w2 A-frags (block-invariant): lane = channel ch*16+col, k = ks*32+quad*8+j
    H8 wf[2][2];
    #pragma unroll
    for (int ch = 0; ch < 2; ++ch)
        #pragma unroll
        for (int ks = 0; ks < 2; ++ks) {
            const f32x4* wr = (const f32x4*)(w2 + (ch * 16 + col) * 64 + ks * 32 + quad * 8);
            const f32x4 w0 = wr[0], w1v = wr[1];
            wf[ch][ks].h2[0] = pkrtz(w0[0], w0[1]);
            wf[ch][ks].h2[1] = pkrtz(w0[2], w0[3]);
            wf[ch][ks].h2[2] = pkrtz(w1v[0], w1v[1]);
            wf[ch][ks].h2[3] = pkrtz(w1v[2], w1v[3]);
        }
    // epilogue coefficients: lane's channels are quad*4+r (accA) / 16+quad*4+r (accB)
    const f32x4 b2A = *(const f32x4*)(b2 + quad * 4);
    const f32x4 b2B = *(const f32x4*)(b2 + 16 + quad * 4);
    const f32x4 w3A = *(const f32x4*)(w3 + quad * 4);
    const f32x4 w3B = *(const f32x4*)(w3 + 16 + quad * 4);
    const float b3v = b3[0];

    __syncthreads();

    // loop-invariant hj fragments (this wave's 16 j's; lane's j = wj*16+col)
    const int hjb = (wj * 16 + col) * HH + quad * 8;
    const f16x8 hj0 = *(const f16x8*)&hjL[hjb];        // ks=0
    const f16x8 hj1 = *(const f16x8*)&hjL[hjb + 32];   // ks=1

    float* mypart = &part[wid * 16 * PSTR];

    #pragma unroll 8
    for (int it = 0; it < 16; ++it) {
        const int base = (wi * 16 + it) * HH + quad * 8;
        // hi broadcast reads (same addr across the 16 lanes of a quad)
        const f16x8 x0 = *(const f16x8*)&hiL[base];
        const f16x8 x1 = *(const f16x8*)&hiL[base + 32];

        // h = relu(hi + hj), all fp16 packed -> MFMA operand directly
        const f16x8 f0 = hmax0(x0 + hj0);
        const f16x8 f1 = hmax0(x1 + hj1);

        f32x4 accA = b2A;   // b2 folded into accumulator init
        f32x4 accB = b2B;
        accA = __builtin_amdgcn_mfma_f32_16x16x32_f16(wf[0][0].v, f0, accA, 0, 0, 0);
        accA = __builtin_amdgcn_mfma_f32_16x16x32_f16(wf[0][1].v, f1, accA, 0, 0, 0);
        accB = __builtin_amdgcn_mfma_f32_16x16x32_f16(wf[1][0].v, f0, accB, 0, 0, 0);
        accB = __builtin_amdgcn_mfma_f32_16x16x32_f16(wf[1][1].v, f1, accB, 0, 0, 0);

        // relu + w3 partial dot over this lane's 8 channels; one LDS partial
        const f32x4 ra = vmax0(accA);
        const f32x4 rb = vmax0(accB);
        const f32x4 t4 = ra * w3A + rb * w3B;
        mypart[it * PSTR + quad * 16 + col] = (t4[0] + t4[1]) + (t4[2] + t4[3]);
    }

    // ---- deferred wave-local epilogue (same-wave producer: no barrier) ----
    {
        const int sub = lane & 3;            // col group (4 cols each)
        const int itx = lane >> 2;           // 0..15 -> i row
        const float* pr = &mypart[itx * PSTR + sub * 4];
        const f32x4 s = *(const f32x4*)(pr)
                      + *(const f32x4*)(pr + 16)
                      + *(const f32x4*)(pr + 32)
                      + *(const f32x4*)(pr + 48);
        const int i  = i0 + wi * 16 + itx;
        const int jb = j0 + wj * 16 + sub * 4;
        float4 o;
        o.x = (jb + 0 > i) ? 1.f / (1.f + __expf(-(s[0] + b3v))) : 0.f;
        o.y = (jb + 1 > i) ? 1.f / (1.f + __expf(-(s[1] + b3v))) : 0.f;
        o.z = (jb + 2 > i) ? 1.f / (1.f + __expf(-(s[2] + b3v))) : 0.f;
        o.w = (jb + 3 > i) ? 1.f / (1.f + __expf(-(s[3] + b3v))) : 0.f;
        *(float4*)(out + (size_t)i * NROWS + jb) = o;
    }
}

extern "C" void kernel_launch(void* const* d_in, const int* in_sizes, int n_in,
                              void* d_out, int out_size, void* d_ws, size_t ws_size,
                              hipStream_t stream) {
    const int*   subj_idx   = (const int*)d_in[0];
    const int*   rel_idx    = (const int*)d_in[1];
    const int*   obj_idx    = (const int*)d_in[2];
    const float* subj_table = (const float*)d_in[3];
    const float* rel_table  = (const float*)d_in[4];
    const float* obj_table  = (const float*)d_in[5];
    const float* proj_w     = (const float*)d_in[6];
    const float* proj_b     = (const float*)d_in[7];
    const float* w1         = (const float*)d_in[8];
    const float* b1         = (const float*)d_in[9];
    const float* w2         = (const float*)d_in[10];
    const float* b2         = (const float*)d_in[11];
    const float* w3         = (const float*)d_in[12];
    const float* b3         = (const float*)d_in[13];
    float* out = (float*)d_out;
    float* ws  = (float*)d_ws;

    tab_kernel<<<dim3(84), dim3(256), 0, stream>>>(
        subj_table, rel_table, obj_table, proj_w, proj_b, w1, b1, ws);

    pair_kernel<<<dim3(NROWS / 32, NROWS / 32), dim3(256), 0, stream>>>(
        subj_idx, rel_idx, obj_idx, ws, w2, b2, w3, b3, out);
}